// Round 2
// baseline (1474.624 us; speedup 1.0000x reference)
//
#include <hip/hip_runtime.h>
#include <hip/hip_bf16.h>

typedef __hip_bfloat16 bf16;

#define TB 8
#define RSQRT8    0.35355339059327373f
#define RSQRT128  0.08838834764831845f
#define RSQRT192  0.07216878364870323f
#define RSQRT64   0.125f
#define INV_SQRT3 0.57735026918962576f
#define SEG_NORM  0.25f       /* 1/sqrt(16) */
#define C_HALF    0.70710678118654752f
#define SQ23      0.81649658092772603f
#define SQ13      0.57735026918962576f

__device__ __forceinline__ float b2f(bf16 x) { return __bfloat162float(x); }
__device__ __forceinline__ bf16  f2b(float x) { return __float2bfloat16(x); }
__device__ __forceinline__ float silu_f(float x) { return x / (1.0f + __expf(-x)); }

template<typename T> __device__ __forceinline__ float ldf(const T* p, size_t i);
template<> __device__ __forceinline__ float ldf<float>(const float* p, size_t i) { return p[i]; }
template<> __device__ __forceinline__ float ldf<bf16>(const bf16*  p, size_t i) { return b2f(p[i]); }

template<typename T> __device__ __forceinline__ void stf(T* p, size_t i, float v);
template<> __device__ __forceinline__ void stf<float>(float* p, size_t i, float v) { p[i] = v; }
template<> __device__ __forceinline__ void stf<bf16 >(bf16*  p, size_t i, float v) { p[i] = f2b(v); }

// ---------------------------------------------------------------------------
// Dtype sniffer: decide whether float tensors are bf16 (flag=1) or fp32 (flag=0).
// Reads 64 32-bit words of edge_attr. If the buffer holds bf16, the LOW 16 bits
// of each word are a real bf16 value of ~N(0,1) -> exponent field in [100,140]
// essentially always. If fp32, low 16 bits are mantissa noise -> ~16% hit rate.
// ---------------------------------------------------------------------------
__global__ void sniff_dtype(const unsigned int* __restrict__ w, int* __restrict__ flag)
{
    int lane = threadIdx.x;
    unsigned int v = w[lane];
    unsigned int elo = (v >> 7) & 0xFF;          // bf16 exponent field of low half
    bool sane = (elo >= 100 && elo <= 140);
    unsigned long long mask = __ballot(sane);
    if (lane == 0) *flag = (__popcll(mask) >= 32) ? 1 : 0;
}

// ---------------------------------------------------------------------------
// Phase A: lat = mlp2(inv, W2b0, W2b1); w = lat @ Wenv0; env_weight ->
// stores lat, feat (bf16 carriers) and atomically accumulates env0[center] (fp32).
// ---------------------------------------------------------------------------
template<typename T>
__global__ __launch_bounds__(128) void phaseA(
    const int* __restrict__ dflag, int want,
    const int* __restrict__ eidx, const T* __restrict__ attr,
    const T* __restrict__ inv,
    const T* __restrict__ W2b0, const T* __restrict__ W2b1,
    const T* __restrict__ Wenv0,
    bf16* __restrict__ latbuf, bf16* __restrict__ featbuf,
    float* __restrict__ env0, int E)
{
    if (*dflag != want) return;
    const int tid = threadIdx.x;
    const int e0 = blockIdx.x * TB;
    const int m = tid >> 2, j = tid & 3;

    __shared__ float sx[TB][8];
    __shared__ float sbuf[TB][128];
    __shared__ float slat[TB][128];
    __shared__ float sw[TB][128];
    __shared__ float sattr[TB][4];
    __shared__ int   sc[TB];

    if (tid < TB * 8) {                      // invariants: threads 0..63
        int t = tid >> 3, k = tid & 7;
        int e = min(e0 + t, E - 1);
        sx[t][k] = ldf(inv, (size_t)e * 8 + k);
    } else if (tid < TB * 8 + TB * 4) {      // attr: threads 64..95
        int q = tid - TB * 8;
        int t = q >> 2, jj = q & 3;
        int e = min(e0 + t, E - 1);
        sattr[t][jj] = ldf(attr, (size_t)e * 4 + jj);
    } else if (tid < TB * 8 + TB * 4 + TB) { // centers: threads 96..103
        int t = tid - TB * 8 - TB * 4;
        sc[t] = eidx[min(e0 + t, E - 1)];
    }
    __syncthreads();

    float acc[TB];
#pragma unroll
    for (int t = 0; t < TB; t++) acc[t] = 0.f;
    for (int k = 0; k < 8; k++) {
        float wv = ldf(W2b0, k * 128 + tid);
#pragma unroll
        for (int t = 0; t < TB; t++) acc[t] = fmaf(sx[t][k], wv, acc[t]);
    }
#pragma unroll
    for (int t = 0; t < TB; t++) sbuf[t][tid] = silu_f(acc[t] * RSQRT8);
    __syncthreads();

#pragma unroll
    for (int t = 0; t < TB; t++) acc[t] = 0.f;
    for (int k = 0; k < 128; k++) {
        float wv = ldf(W2b1, k * 128 + tid);
#pragma unroll
        for (int t = 0; t < TB; t++) acc[t] = fmaf(sbuf[t][k], wv, acc[t]);
    }
#pragma unroll
    for (int t = 0; t < TB; t++) {
        float l = acc[t] * RSQRT128;
        slat[t][tid] = l;
        int e = e0 + t;
        if (e < E) latbuf[(size_t)e * 128 + tid] = f2b(l);
    }
    __syncthreads();

#pragma unroll
    for (int t = 0; t < TB; t++) acc[t] = 0.f;
    for (int k = 0; k < 128; k++) {
        float wv = ldf(Wenv0, k * 128 + tid);
#pragma unroll
        for (int t = 0; t < TB; t++) acc[t] = fmaf(slat[t][k], wv, acc[t]);
    }
#pragma unroll
    for (int t = 0; t < TB; t++) sw[t][tid] = acc[t] * RSQRT128;
    __syncthreads();

    // env_weight: w.reshape(32,2); out[m][0]=w[2m]*attr[0], out[m][j]=w[2m+1]*attr[j]
#pragma unroll
    for (int t = 0; t < TB; t++) {
        int e = e0 + t;
        if (e < E) {
            float a  = sattr[t][j];
            float wf = (j == 0) ? sw[t][2 * m] : sw[t][2 * m + 1];
            float we = (j == 0) ? sw[t][64 + 2 * m] : sw[t][64 + 2 * m + 1];
            featbuf[(size_t)e * 128 + tid] = f2b(wf * a);
            atomicAdd(&env0[(size_t)sc[t] * 128 + tid], we * a);
        }
    }
}

// ---------------------------------------------------------------------------
// Phase B: gather env0, tensor products, Ws0/Wv0 mix -> feat2; new_lat MLP;
// lat2 = sqrt(.5)*(lat+new_lat); w1 = lat2@Wenv1; scatter env1.
// ---------------------------------------------------------------------------
template<typename T>
__global__ __launch_bounds__(128) void phaseB(
    const int* __restrict__ dflag, int want,
    const int* __restrict__ eidx, const T* __restrict__ attr,
    const float* __restrict__ env0,
    const T* __restrict__ Ws0, const T* __restrict__ Wv0,
    const T* __restrict__ Wlat1_0, const T* __restrict__ Wlat1_1,
    const T* __restrict__ Wenv1,
    bf16* __restrict__ latbuf, bf16* __restrict__ featbuf,
    float* __restrict__ env1, int E)
{
    if (*dflag != want) return;
    const int tid = threadIdx.x;
    const int e0 = blockIdx.x * TB;
    const int m = tid >> 2, j = tid & 3;

    __shared__ float slat[TB][128];
    __shared__ float sf[TB][128];
    __shared__ float sg[TB][128];
    __shared__ float sscal[TB][64];
    __shared__ float sh[TB][128];
    __shared__ float sw1[TB][64];
    __shared__ float sattr[TB][4];
    __shared__ int   sc[TB];

    if (tid < TB) {
        sc[tid] = eidx[min(e0 + tid, E - 1)];
    } else if (tid >= 64 && tid < 64 + TB * 4) {
        int q = tid - 64;
        int t = q >> 2, jj = q & 3;
        int e = min(e0 + t, E - 1);
        sattr[t][jj] = ldf(attr, (size_t)e * 4 + jj);
    }
    __syncthreads();

#pragma unroll
    for (int t = 0; t < TB; t++) {
        int e = min(e0 + t, E - 1);
        slat[t][tid] = b2f(latbuf[(size_t)e * 128 + tid]);
        sf[t][tid]   = b2f(featbuf[(size_t)e * 128 + tid]);
        sg[t][tid]   = env0[(size_t)sc[t] * 128 + tid] * SEG_NORM;
    }
    __syncthreads();

    // scalars interleaved: sscal[2m]=out_ss[m], sscal[2m+1]=out_vv[m]
    if (tid < 64) {
        int mm = tid >> 1;
        if (tid & 1) {
#pragma unroll
            for (int t = 0; t < TB; t++) {
                float s = sf[t][4*mm+1]*sg[t][4*mm+1]
                        + sf[t][4*mm+2]*sg[t][4*mm+2]
                        + sf[t][4*mm+3]*sg[t][4*mm+3];
                sscal[t][tid] = s * INV_SQRT3;
            }
        } else {
#pragma unroll
            for (int t = 0; t < TB; t++)
                sscal[t][tid] = sf[t][4*mm] * sg[t][4*mm];
        }
    }
    __syncthreads();

    // feat2[tid]: j==0 -> s_out[m] = s_in @ Ws0 /8 ; j>0 -> v_out[m][j-1]
    float acc[TB];
#pragma unroll
    for (int t = 0; t < TB; t++) acc[t] = 0.f;
    if (j == 0) {
        for (int c = 0; c < 32; c++) {
            float w0 = ldf(Ws0, c * 32 + m);          // s_in[c]    = out_ss[c] = sscal[2c]
            float w1 = ldf(Ws0, (32 + c) * 32 + m);   // s_in[32+c] = out_vv[c] = sscal[2c+1]
#pragma unroll
            for (int t = 0; t < TB; t++)
                acc[t] += sscal[t][2*c] * w0 + sscal[t][2*c+1] * w1;
        }
#pragma unroll
        for (int t = 0; t < TB; t++) acc[t] *= RSQRT64;
    } else {
        for (int c = 0; c < 32; c++) {
            float w0 = ldf(Wv0, c * 32 + m);          // v_in[c]    = out_sv[c] = x0*yv/√3
            float w1 = ldf(Wv0, (32 + c) * 32 + m);   // v_in[32+c] = out_vs[c] = xv*y0/√3
#pragma unroll
            for (int t = 0; t < TB; t++)
                acc[t] += sf[t][4*c] * sg[t][4*c + j] * w0
                        + sf[t][4*c + j] * sg[t][4*c] * w1;
        }
#pragma unroll
        for (int t = 0; t < TB; t++) acc[t] *= RSQRT64 * INV_SQRT3;
    }
#pragma unroll
    for (int t = 0; t < TB; t++) {
        int e = e0 + t;
        if (e < E) featbuf[(size_t)e * 128 + tid] = f2b(acc[t]);
    }

    // new_lat = mlp2(concat(lat, scalars), Wlat1_0, Wlat1_1)
#pragma unroll
    for (int t = 0; t < TB; t++) acc[t] = 0.f;
    for (int k = 0; k < 128; k++) {
        float wv = ldf(Wlat1_0, k * 128 + tid);
#pragma unroll
        for (int t = 0; t < TB; t++) acc[t] = fmaf(slat[t][k], wv, acc[t]);
    }
    for (int k = 0; k < 64; k++) {
        float wv = ldf(Wlat1_0, (128 + k) * 128 + tid);
#pragma unroll
        for (int t = 0; t < TB; t++) acc[t] = fmaf(sscal[t][k], wv, acc[t]);
    }
#pragma unroll
    for (int t = 0; t < TB; t++) sh[t][tid] = silu_f(acc[t] * RSQRT192);
    __syncthreads();

#pragma unroll
    for (int t = 0; t < TB; t++) acc[t] = 0.f;
    for (int k = 0; k < 128; k++) {
        float wv = ldf(Wlat1_1, k * 128 + tid);
#pragma unroll
        for (int t = 0; t < TB; t++) acc[t] = fmaf(sh[t][k], wv, acc[t]);
    }
    float l2[TB];
#pragma unroll
    for (int t = 0; t < TB; t++) {
        l2[t] = C_HALF * (slat[t][tid] + acc[t] * RSQRT128);
        int e = e0 + t;
        if (e < E) latbuf[(size_t)e * 128 + tid] = f2b(l2[t]);
    }
    // sf reads all happen before the sh barrier above -> safe to overwrite with lat2
#pragma unroll
    for (int t = 0; t < TB; t++) sf[t][tid] = l2[t];
    __syncthreads();

    if (tid < 64) {
#pragma unroll
        for (int t = 0; t < TB; t++) acc[t] = 0.f;
        for (int k = 0; k < 128; k++) {
            float wv = ldf(Wenv1, k * 64 + tid);
#pragma unroll
            for (int t = 0; t < TB; t++) acc[t] = fmaf(sf[t][k], wv, acc[t]);
        }
#pragma unroll
        for (int t = 0; t < TB; t++) sw1[t][tid] = acc[t] * RSQRT128;
    }
    __syncthreads();

#pragma unroll
    for (int t = 0; t < TB; t++) {
        int e = e0 + t;
        if (e < E) {
            float a  = sattr[t][j];
            float we = (j == 0) ? sw1[t][2 * m] : sw1[t][2 * m + 1];
            atomicAdd(&env1[(size_t)sc[t] * 128 + tid], we * a);
        }
    }
}

// ---------------------------------------------------------------------------
// Phase C: gather env1, scalars1, final MLP, output mix.
// ---------------------------------------------------------------------------
template<typename T>
__global__ __launch_bounds__(128) void phaseC(
    const int* __restrict__ dflag, int want,
    const int* __restrict__ eidx, const float* __restrict__ env1,
    const T* __restrict__ Wfin0, const T* __restrict__ Wfin1,
    const bf16* __restrict__ latbuf, const bf16* __restrict__ featbuf,
    T* __restrict__ outp, int E)
{
    if (*dflag != want) return;
    const int tid = threadIdx.x;
    const int e0 = blockIdx.x * TB;

    __shared__ float slat[TB][128];
    __shared__ float sprod[TB][128];
    __shared__ float sscal[TB][64];
    __shared__ float sh[TB][128];
    __shared__ int   sc[TB];

    if (tid < TB) sc[tid] = eidx[min(e0 + tid, E - 1)];
    __syncthreads();

#pragma unroll
    for (int t = 0; t < TB; t++) {
        int e = min(e0 + t, E - 1);
        slat[t][tid] = b2f(latbuf[(size_t)e * 128 + tid]);
        float f = b2f(featbuf[(size_t)e * 128 + tid]);
        float g = env1[(size_t)sc[t] * 128 + tid] * SEG_NORM;
        sprod[t][tid] = f * g;
    }
    __syncthreads();

    if (tid < 64) {
        int mm = tid >> 1;
        if (tid & 1) {
#pragma unroll
            for (int t = 0; t < TB; t++)
                sscal[t][tid] = (sprod[t][4*mm+1] + sprod[t][4*mm+2] + sprod[t][4*mm+3]) * INV_SQRT3;
        } else {
#pragma unroll
            for (int t = 0; t < TB; t++)
                sscal[t][tid] = sprod[t][4*mm];
        }
    }
    __syncthreads();

    float acc[TB];
#pragma unroll
    for (int t = 0; t < TB; t++) acc[t] = 0.f;
    for (int k = 0; k < 128; k++) {
        float wv = ldf(Wfin0, k * 128 + tid);
#pragma unroll
        for (int t = 0; t < TB; t++) acc[t] = fmaf(slat[t][k], wv, acc[t]);
    }
    for (int k = 0; k < 64; k++) {
        float wv = ldf(Wfin0, (128 + k) * 128 + tid);
#pragma unroll
        for (int t = 0; t < TB; t++) acc[t] = fmaf(sscal[t][k], wv, acc[t]);
    }
#pragma unroll
    for (int t = 0; t < TB; t++) sh[t][tid] = silu_f(acc[t] * RSQRT192);
    __syncthreads();

#pragma unroll
    for (int t = 0; t < TB; t++) acc[t] = 0.f;
    for (int k = 0; k < 128; k++) {
        float wv = ldf(Wfin1, k * 128 + tid);
#pragma unroll
        for (int t = 0; t < TB; t++) acc[t] = fmaf(sh[t][k], wv, acc[t]);
    }
#pragma unroll
    for (int t = 0; t < TB; t++) {
        int e = e0 + t;
        if (e < E) {
            float nl = acc[t] * RSQRT128;
            stf(outp, (size_t)e * 128 + tid, SQ23 * slat[t][tid] + SQ13 * nl);
        }
    }
}

extern "C" void kernel_launch(void* const* d_in, const int* in_sizes, int n_in,
                              void* d_out, int out_size, void* d_ws, size_t ws_size,
                              hipStream_t stream)
{
    const int E  = in_sizes[0] / 2;   // edge_index is (2, E)
    const int NN = 12500;             // num_nodes (fixed by problem setup)

    const int* eidx = (const int*)d_in[0];

    // workspace carve: [flag 256B][lat bf16 E*128][feat bf16 E*128][env0 f32][env1 f32]
    char*  ws      = (char*)d_ws;
    int*   dflag   = (int*)ws;
    bf16*  latbuf  = (bf16*)(ws + 256);
    bf16*  featbuf = latbuf + (size_t)E * 128;
    float* env0    = (float*)(featbuf + (size_t)E * 128);
    float* env1    = env0 + (size_t)NN * 128;

    sniff_dtype<<<1, 64, 0, stream>>>((const unsigned int*)d_in[1], dflag);
    hipMemsetAsync(env0, 0, (size_t)NN * 128 * 2 * sizeof(float), stream);

    const int nb = (E + TB - 1) / TB;

    // fp32 pipeline (flag==0)
    phaseA<float><<<nb, 128, 0, stream>>>(dflag, 0, eidx,
        (const float*)d_in[1], (const float*)d_in[2],
        (const float*)d_in[3], (const float*)d_in[4], (const float*)d_in[5],
        latbuf, featbuf, env0, E);
    // bf16 pipeline (flag==1)
    phaseA<bf16><<<nb, 128, 0, stream>>>(dflag, 1, eidx,
        (const bf16*)d_in[1], (const bf16*)d_in[2],
        (const bf16*)d_in[3], (const bf16*)d_in[4], (const bf16*)d_in[5],
        latbuf, featbuf, env0, E);

    phaseB<float><<<nb, 128, 0, stream>>>(dflag, 0, eidx,
        (const float*)d_in[1], env0,
        (const float*)d_in[9], (const float*)d_in[10],
        (const float*)d_in[6], (const float*)d_in[7], (const float*)d_in[8],
        latbuf, featbuf, env1, E);
    phaseB<bf16><<<nb, 128, 0, stream>>>(dflag, 1, eidx,
        (const bf16*)d_in[1], env0,
        (const bf16*)d_in[9], (const bf16*)d_in[10],
        (const bf16*)d_in[6], (const bf16*)d_in[7], (const bf16*)d_in[8],
        latbuf, featbuf, env1, E);

    phaseC<float><<<nb, 128, 0, stream>>>(dflag, 0, eidx, env1,
        (const float*)d_in[11], (const float*)d_in[12],
        latbuf, featbuf, (float*)d_out, E);
    phaseC<bf16><<<nb, 128, 0, stream>>>(dflag, 1, eidx, env1,
        (const bf16*)d_in[11], (const bf16*)d_in[12],
        latbuf, featbuf, (bf16*)d_out, E);
}